// Round 1
// baseline (218.295 us; speedup 1.0000x reference)
//
#include <hip/hip_runtime.h>

#define N_NODES 100000
#define N_EDGES 1600000
#define VOCAB   1000
#define EMB_DIM 64
#define OUT_DIM 32

#define NB3 128      // blocks in coeff kernel (must match reducer)
#define T3  512

__device__ __forceinline__ void fatomic_add(float* p, float v) {
    unsafeAtomicAdd(p, v);   // hw global_atomic_add_f32 / ds_add_f32 on gfx950
}

// ---- K1: init deg = 1.0 (self-loop weight) --------------------------------
__global__ void k_init_deg(float* __restrict__ deg) {
    int i = blockIdx.x * blockDim.x + threadIdx.x;
    if (i < N_NODES) deg[i] = 1.0f;
}

// ---- K2: deg[col[e]] += w[e] ----------------------------------------------
__global__ void k_deg(const int* __restrict__ col, const float* __restrict__ w,
                      float* __restrict__ deg) {
    int i = blockIdx.x * blockDim.x + threadIdx.x;
    if (i < N_EDGES) fatomic_add(&deg[col[i]], w[i]);
}

// ---- K3: per-block LDS histogram of coeff over vocab ----------------------
// items 0..E-1: edges,  items E..E+N-1: self loops
__global__ void __launch_bounds__(T3) k_coeff(
        const int* __restrict__ row, const int* __restrict__ col,
        const float* __restrict__ w, const float* __restrict__ deg,
        const int* __restrict__ node_seq, float* __restrict__ gcoeff) {
    __shared__ float lc[VOCAB];
    for (int i = threadIdx.x; i < VOCAB; i += blockDim.x) lc[i] = 0.0f;
    __syncthreads();

    const int total  = N_EDGES + N_NODES;
    const int stride = gridDim.x * blockDim.x;
    for (int i = blockIdx.x * blockDim.x + threadIdx.x; i < total; i += stride) {
        if (i < N_EDGES) {
            int r = row[i];
            int c = col[i];
            float norm = __frsqrt_rn(deg[r]) * w[i] * __frsqrt_rn(deg[c]);
            fatomic_add(&lc[node_seq[r]], norm);
        } else {
            int n = i - N_EDGES;
            float dis = __frsqrt_rn(deg[n]);
            fatomic_add(&lc[node_seq[n]], dis * dis);   // self loop, weight 1
        }
    }
    __syncthreads();
    for (int i = threadIdx.x; i < VOCAB; i += blockDim.x)
        gcoeff[blockIdx.x * VOCAB + i] = lc[i];
}

// ---- K4a: coeff[v] = sum over NB3 block partials --------------------------
__global__ void k_reduce_coeff(const float* __restrict__ gcoeff,
                               float* __restrict__ coeff) {
    int v = blockIdx.x * blockDim.x + threadIdx.x;
    if (v < VOCAB) {
        float s = 0.0f;
        for (int b = 0; b < NB3; ++b) s += gcoeff[b * VOCAB + v];
        coeff[v] = s;
    }
}

// ---- K4b: out[d] = (sum_v coeff[v] * (emb@W)[v,d]) / N + b[d] -------------
// computed as t[k] = sum_v coeff[v]*emb[v,k]; out[d] = sum_k t[k]*W[k,d]
__global__ void __launch_bounds__(1024) k_final(
        const float* __restrict__ coeff, const float* __restrict__ emb,
        const float* __restrict__ W, const float* __restrict__ bias,
        float* __restrict__ out) {
    __shared__ float lc[VOCAB];
    __shared__ float tk[16 * 64];
    int t = threadIdx.x;
    for (int v = t; v < VOCAB; v += 1024) lc[v] = coeff[v];
    __syncthreads();

    int k = t & 63;
    int g = t >> 6;            // 0..15
    float p = 0.0f;
    for (int v = g; v < VOCAB; v += 16) p += lc[v] * emb[v * EMB_DIM + k];
    tk[g * 64 + k] = p;
    __syncthreads();

    if (t < 64) {
        float s = 0.0f;
        for (int gg = 0; gg < 16; ++gg) s += tk[gg * 64 + t];
        tk[t] = s;             // reduced t[k] lands in tk[0..63]
    }
    __syncthreads();

    if (t < OUT_DIM) {
        float s = 0.0f;
        for (int kk = 0; kk < EMB_DIM; ++kk) s += tk[kk] * W[kk * OUT_DIM + t];
        out[t] = s * (1.0f / (float)N_NODES) + bias[t];
    }
}

extern "C" void kernel_launch(void* const* d_in, const int* in_sizes, int n_in,
                              void* d_out, int out_size, void* d_ws, size_t ws_size,
                              hipStream_t stream) {
    const int*   node_seq = (const int*)  d_in[0];
    const int*   eidx     = (const int*)  d_in[1];   // [2, E] flat
    const float* ew       = (const float*)d_in[2];
    const float* emb      = (const float*)d_in[3];
    const float* W        = (const float*)d_in[4];
    const float* b        = (const float*)d_in[5];
    float*       out      = (float*)d_out;

    const int* row = eidx;            // edge_index[0]
    const int* col = eidx + N_EDGES;  // edge_index[1]

    float* deg    = (float*)d_ws;                 // [N_NODES]
    float* gcoeff = deg + N_NODES;                // [NB3 * VOCAB]
    float* coeff  = gcoeff + NB3 * VOCAB;         // [VOCAB]

    k_init_deg<<<(N_NODES + 255) / 256, 256, 0, stream>>>(deg);
    k_deg<<<(N_EDGES + 255) / 256, 256, 0, stream>>>(col, ew, deg);
    k_coeff<<<NB3, T3, 0, stream>>>(row, col, ew, deg, node_seq, gcoeff);
    k_reduce_coeff<<<(VOCAB + 255) / 256, 256, 0, stream>>>(gcoeff, coeff);
    k_final<<<1, 1024, 0, stream>>>(coeff, emb, W, b, out);
}

// Round 2
// 156.710 us; speedup vs baseline: 1.3930x; 1.3930x over previous
//
#include <hip/hip_runtime.h>

#define N_NODES 100000
#define N_EDGES 1600000
#define VOCAB   1000
#define EMB_DIM 64
#define OUT_DIM 32

// ---- bucketing parameters -------------------------------------------------
#define BKT_BITS 9
#define BKT_SIZE 512                                   // nodes per bucket
#define NBKT ((N_NODES + BKT_SIZE - 1) / BKT_SIZE)     // 196
#define CAP  12288                                     // capacity per bucket (avg 8163)
#define NSB  256                                       // scatter blocks
#define CHUNK (N_EDGES / NSB)                          // 6250 (exact)

// ---- coeff kernel parameters ---------------------------------------------
#define NBC 256
#define TBC 512

__device__ __forceinline__ void fatomic_add(float* p, float v) {
    unsafeAtomicAdd(p, v);   // ds_add_f32 / global_atomic_add_f32
}

// ===== main path (bucketed degree) =========================================

__global__ void k_init(int* __restrict__ cursors) {
    int i = blockIdx.x * blockDim.x + threadIdx.x;
    if (i < NBKT) cursors[i] = i * CAP;
}

// scatter (col,w) records into per-bucket segments; only ~50K global atomics
__global__ void __launch_bounds__(256) k_scatter(
        const int* __restrict__ col, const float* __restrict__ w,
        int* __restrict__ cursors, uint2* __restrict__ recs) {
    __shared__ int lcnt[NBKT];
    __shared__ int lbase[NBKT];
    for (int i = threadIdx.x; i < NBKT; i += 256) lcnt[i] = 0;
    __syncthreads();
    const int e0 = blockIdx.x * CHUNK;
    for (int i = threadIdx.x; i < CHUNK; i += 256)
        atomicAdd(&lcnt[col[e0 + i] >> BKT_BITS], 1);
    __syncthreads();
    for (int i = threadIdx.x; i < NBKT; i += 256) {
        lbase[i] = atomicAdd(&cursors[i], lcnt[i]);   // batched global cursor
        lcnt[i] = 0;                                  // reuse as local offset
    }
    __syncthreads();
    for (int i = threadIdx.x; i < CHUNK; i += 256) {
        int c = col[e0 + i];                          // L1/L2-warm second read
        int b = c >> BKT_BITS;
        int pos = lbase[b] + atomicAdd(&lcnt[b], 1);
        recs[pos] = make_uint2((unsigned)c, __float_as_uint(w[e0 + i]));
    }
}

// per-bucket LDS accumulate -> dis[n] = rsqrt(1 + sum_w)
__global__ void __launch_bounds__(256) k_bucket_dis(
        const uint2* __restrict__ recs, const int* __restrict__ cursors,
        float* __restrict__ dis) {
    __shared__ float acc[BKT_SIZE];
    int b = blockIdx.x;
    for (int i = threadIdx.x; i < BKT_SIZE; i += 256) acc[i] = 0.0f;
    __syncthreads();
    const int base = b * CAP;
    const int cnt = cursors[b] - base;
    for (int i = threadIdx.x; i < cnt; i += 256) {
        uint2 r = recs[base + i];
        fatomic_add(&acc[(int)r.x - (b << BKT_BITS)], __uint_as_float(r.y));
    }
    __syncthreads();
    const int n0 = b << BKT_BITS;
    for (int i = threadIdx.x; i < BKT_SIZE && n0 + i < N_NODES; i += 256)
        dis[n0 + i] = __frsqrt_rn(1.0f + acc[i]);
}

// ===== fallback path (if ws too small): direct atomics =====================

__global__ void k_init_deg(float* __restrict__ deg) {
    int i = blockIdx.x * blockDim.x + threadIdx.x;
    if (i < N_NODES) deg[i] = 1.0f;
}
__global__ void k_deg(const int* __restrict__ col, const float* __restrict__ w,
                      float* __restrict__ deg) {
    int i = blockIdx.x * blockDim.x + threadIdx.x;
    if (i < N_EDGES) fatomic_add(&deg[col[i]], w[i]);
}
__global__ void k_dis(float* __restrict__ deg) {
    int i = blockIdx.x * blockDim.x + threadIdx.x;
    if (i < N_NODES) deg[i] = __frsqrt_rn(deg[i]);
}

// ===== coeff histogram over vocab ==========================================

__global__ void __launch_bounds__(TBC) k_coeff(
        const int* __restrict__ row, const int* __restrict__ col,
        const float* __restrict__ w, const float* __restrict__ dis,
        const int* __restrict__ node_seq, float* __restrict__ gcoeff) {
    __shared__ float lc[VOCAB];
    for (int i = threadIdx.x; i < VOCAB; i += TBC) lc[i] = 0.0f;
    __syncthreads();
    const int total = N_EDGES + N_NODES;
    const int stride = NBC * TBC;
    for (int i = blockIdx.x * TBC + threadIdx.x; i < total; i += stride) {
        if (i < N_EDGES) {
            int r = row[i];
            float norm = dis[r] * w[i] * dis[col[i]];
            fatomic_add(&lc[node_seq[r]], norm);
        } else {
            int n = i - N_EDGES;
            float d = dis[n];
            fatomic_add(&lc[node_seq[n]], d * d);   // self loop, weight 1
        }
    }
    __syncthreads();
    for (int i = threadIdx.x; i < VOCAB; i += TBC)
        gcoeff[blockIdx.x * VOCAB + i] = lc[i];
}

// one wave per vocab slot reduces the NBC partials
__global__ void __launch_bounds__(256) k_reduce(
        const float* __restrict__ gcoeff, float* __restrict__ coeff) {
    int g = blockIdx.x * 256 + threadIdx.x;
    int v = g >> 6;
    int l = g & 63;
    if (v >= VOCAB) return;
    float s = 0.0f;
    for (int b = l; b < NBC; b += 64) s += gcoeff[b * VOCAB + v];
    for (int off = 32; off > 0; off >>= 1) s += __shfl_down(s, off, 64);
    if (l == 0) coeff[v] = s;
}

// out[d] = (sum_v coeff[v]*(emb@W)[v,d])/N + b[d]  via t[k]=sum_v coeff*emb
__global__ void __launch_bounds__(1024) k_final(
        const float* __restrict__ coeff, const float* __restrict__ emb,
        const float* __restrict__ W, const float* __restrict__ bias,
        float* __restrict__ out) {
    __shared__ float lc[VOCAB];
    __shared__ float tk[16 * 64];
    int t = threadIdx.x;
    for (int v = t; v < VOCAB; v += 1024) lc[v] = coeff[v];
    __syncthreads();

    int k = t & 63;
    int g = t >> 6;
    float p = 0.0f;
    for (int v = g; v < VOCAB; v += 16) p += lc[v] * emb[v * EMB_DIM + k];
    tk[g * 64 + k] = p;
    __syncthreads();

    if (t < 64) {
        float s = 0.0f;
        for (int gg = 0; gg < 16; ++gg) s += tk[gg * 64 + t];
        tk[t] = s;
    }
    __syncthreads();

    if (t < OUT_DIM) {
        float s = 0.0f;
        for (int kk = 0; kk < EMB_DIM; ++kk) s += tk[kk] * W[kk * OUT_DIM + t];
        out[t] = s * (1.0f / (float)N_NODES) + bias[t];
    }
}

extern "C" void kernel_launch(void* const* d_in, const int* in_sizes, int n_in,
                              void* d_out, int out_size, void* d_ws, size_t ws_size,
                              hipStream_t stream) {
    const int*   node_seq = (const int*)  d_in[0];
    const int*   eidx     = (const int*)  d_in[1];   // [2, E] flat
    const float* ew       = (const float*)d_in[2];
    const float* emb      = (const float*)d_in[3];
    const float* W        = (const float*)d_in[4];
    const float* b        = (const float*)d_in[5];
    float*       out      = (float*)d_out;

    const int* row = eidx;
    const int* col = eidx + N_EDGES;

    char* wsb = (char*)d_ws;
    const size_t REC_BYTES = (size_t)NBKT * CAP * sizeof(uint2);  // ~19.3 MB
    const size_t need = REC_BYTES + 1024 + (size_t)N_NODES * 4
                      + (size_t)NBC * VOCAB * 4 + 4096;

    if (ws_size >= need) {
        uint2* recs    = (uint2*)wsb;
        int*   cursors = (int*)(wsb + REC_BYTES);
        float* dis     = (float*)(wsb + REC_BYTES + 1024);
        float* gcoeff  = dis + N_NODES;
        float* coeff   = gcoeff + (size_t)NBC * VOCAB;

        k_init<<<1, 256, 0, stream>>>(cursors);
        k_scatter<<<NSB, 256, 0, stream>>>(col, ew, cursors, recs);
        k_bucket_dis<<<NBKT, 256, 0, stream>>>(recs, cursors, dis);
        k_coeff<<<NBC, TBC, 0, stream>>>(row, col, ew, dis, node_seq, gcoeff);
        k_reduce<<<(VOCAB * 64 + 255) / 256, 256, 0, stream>>>(gcoeff, coeff);
        k_final<<<1, 1024, 0, stream>>>(coeff, emb, W, b, out);
    } else {
        float* dis    = (float*)wsb;                  // doubles as deg
        float* gcoeff = dis + N_NODES;
        float* coeff  = gcoeff + (size_t)NBC * VOCAB;

        k_init_deg<<<(N_NODES + 255) / 256, 256, 0, stream>>>(dis);
        k_deg<<<(N_EDGES + 255) / 256, 256, 0, stream>>>(col, ew, dis);
        k_dis<<<(N_NODES + 255) / 256, 256, 0, stream>>>(dis);
        k_coeff<<<NBC, TBC, 0, stream>>>(row, col, ew, dis, node_seq, gcoeff);
        k_reduce<<<(VOCAB * 64 + 255) / 256, 256, 0, stream>>>(gcoeff, coeff);
        k_final<<<1, 1024, 0, stream>>>(coeff, emb, W, b, out);
    }
}